// Round 2
// baseline (2911.832 us; speedup 1.0000x reference)
//
#include <hip/hip_runtime.h>
#include <cmath>

#define BB 4
#define NN 4096
#define CC 1024
#define HH 8
#define DD 128
#define MM (BB*NN)   // 16384

// ---------------------------------------------------------------------------
// K1: qk = x @ qk_w + qk_b ; elu+1 ; split -> qbuf (first 1024), kbuf (last)
// fp32 tiled GEMM: 128x128 block tile, 256 threads, 8x8 per thread, BK=16
// ---------------------------------------------------------------------------
__global__ __launch_bounds__(256) void gemm_qk_kernel(
    const float* __restrict__ x, const float* __restrict__ w,
    const float* __restrict__ bias, float* __restrict__ qbuf,
    float* __restrict__ kbuf)
{
    __shared__ float As[16][132];   // As[k][m], +4 pad -> 2-way (free) banks
    __shared__ float Bs[16][128];   // Bs[k][n]
    const int m0 = blockIdx.x * 128;
    const int n0 = blockIdx.y * 128;
    const int tid = threadIdx.x;
    const int tm = (tid >> 4) * 8;
    const int tn = (tid & 15) * 8;
    float acc[8][8] = {};
    for (int k0 = 0; k0 < CC; k0 += 16) {
        #pragma unroll
        for (int i = 0; i < 8; ++i) {
            int e = tid + i * 256;          // 128x16 A tile
            int r = e >> 4, c = e & 15;
            As[c][r] = x[(size_t)(m0 + r) * CC + (k0 + c)];
        }
        #pragma unroll
        for (int i = 0; i < 8; ++i) {
            int e = tid + i * 256;          // 16x128 B tile
            int r = e >> 7, c = e & 127;
            Bs[r][c] = w[(size_t)(k0 + r) * 2048 + (n0 + c)];
        }
        __syncthreads();
        #pragma unroll
        for (int kk = 0; kk < 16; ++kk) {
            float a[8], b[8];
            *(float4*)&a[0] = *(const float4*)&As[kk][tm];
            *(float4*)&a[4] = *(const float4*)&As[kk][tm + 4];
            *(float4*)&b[0] = *(const float4*)&Bs[kk][tn];
            *(float4*)&b[4] = *(const float4*)&Bs[kk][tn + 4];
            #pragma unroll
            for (int i = 0; i < 8; ++i)
                #pragma unroll
                for (int j = 0; j < 8; ++j)
                    acc[i][j] = fmaf(a[i], b[j], acc[i][j]);
        }
        __syncthreads();
    }
    #pragma unroll
    for (int i = 0; i < 8; ++i) {
        const int m = m0 + tm + i;
        #pragma unroll
        for (int j = 0; j < 8; ++j) {
            const int n = n0 + tn + j;
            float v = acc[i][j] + bias[n];
            v = (v > 0.0f) ? (v + 1.0f) : expf(v);   // elu(v)+1
            if (n < CC) qbuf[(size_t)m * CC + n] = v;
            else        kbuf[(size_t)m * CC + (n - CC)] = v;
        }
    }
}

// ---------------------------------------------------------------------------
// K2: kmean[b,c] = mean over n of kbuf[b,n,c]   (split-n + fp32 atomics)
// grid (16, 64): x -> (b, c-chunk of 256); y -> 64-row chunk
// ---------------------------------------------------------------------------
__global__ __launch_bounds__(256) void kmean_kernel(
    const float* __restrict__ kbuf, float* __restrict__ kmean)
{
    const int b = blockIdx.x >> 2;
    const int c = (blockIdx.x & 3) * 256 + threadIdx.x;
    const int n0 = blockIdx.y * 64;
    const float* p = kbuf + (size_t)(b * NN + n0) * CC + c;
    float s = 0.0f;
    for (int r = 0; r < 64; ++r) s += p[(size_t)r * CC];
    atomicAdd(&kmean[b * CC + c], s * (1.0f / (float)NN));
}

// ---------------------------------------------------------------------------
// K3: per row m: z[m,h] = 1/(dot(q_head, kmean_head)+1e-6)  (pre-rope q)
//     then RoPE q,k in place. Row staged in LDS.
// ---------------------------------------------------------------------------
__global__ __launch_bounds__(256) void rope_z_kernel(
    float* __restrict__ qbuf, float* __restrict__ kbuf,
    const float* __restrict__ kmean, float* __restrict__ zbuf)
{
    __shared__ float qs[CC];
    __shared__ float ks2[CC];
    __shared__ float zsum[HH];
    const int m = blockIdx.x;
    const int b = m >> 12;
    const int pos = m & (NN - 1);
    const int tid = threadIdx.x;
    float* qrow = qbuf + (size_t)m * CC;
    float* krow = kbuf + (size_t)m * CC;
    const float* km = kmean + b * CC;
    for (int i = tid; i < CC; i += 256) { qs[i] = qrow[i]; ks2[i] = krow[i]; }
    if (tid < HH) zsum[tid] = 0.0f;
    __syncthreads();
    {   // z partial: thread covers channels 4t..4t+3 (all in head t>>5)
        const int c0 = tid * 4;
        float p = 0.0f;
        #pragma unroll
        for (int i = 0; i < 4; ++i) p = fmaf(qs[c0 + i], km[c0 + i], p);
        atomicAdd(&zsum[tid >> 5], p);
    }
    #pragma unroll
    for (int jj = 0; jj < 2; ++jj) {
        const int j = tid + jj * 256;   // 0..511
        const float theta = 1.0f / powf(10000.0f, (float)j * (1.0f / 512.0f));
        float sv, cv;
        sincosf((float)pos * theta, &sv, &cv);
        const float q0 = qs[2 * j], q1 = qs[2 * j + 1];
        const float k0 = ks2[2 * j], k1 = ks2[2 * j + 1];
        qrow[j]       = cv * q0 - sv * q1;
        qrow[j + 512] = cv * q1 + sv * q0;
        krow[j]       = cv * k0 - sv * k1;
        krow[j + 512] = cv * k1 + sv * k0;
    }
    __syncthreads();
    if (tid < HH) zbuf[(size_t)m * HH + tid] = 1.0f / (zsum[tid] + 1e-6f);
}

// ---------------------------------------------------------------------------
// K4: kv[b,h,d,e] = (1/64) * sum_n kr[b,n,h,d] * x[b,n,h,e]
// split-K over n (16 chunks of 256 rows), fp32 atomics into kv
// ---------------------------------------------------------------------------
__global__ __launch_bounds__(256) void kv_kernel(
    const float* __restrict__ kr, const float* __restrict__ x,
    float* __restrict__ kv)
{
    __shared__ float ksm[8][128];
    __shared__ float vsm[8][128];
    const int bh = blockIdx.x;                 // 0..31
    const int b = bh >> 3, h = bh & 7;
    const int n0 = blockIdx.y * 256;
    const int tid = threadIdx.x;
    const int td = (tid >> 4) * 8;
    const int te = (tid & 15) * 8;
    const float* krp = kr + (size_t)(b * NN + n0) * CC + h * DD;
    const float* xp  = x  + (size_t)(b * NN + n0) * CC + h * DD;
    float acc[8][8] = {};
    for (int r0 = 0; r0 < 256; r0 += 8) {
        #pragma unroll
        for (int i = 0; i < 4; ++i) {
            int e = tid + i * 256;
            int r = e >> 7, c = e & 127;
            ksm[r][c] = krp[(size_t)(r0 + r) * CC + c];
            vsm[r][c] = xp[(size_t)(r0 + r) * CC + c];
        }
        __syncthreads();
        #pragma unroll
        for (int r = 0; r < 8; ++r) {
            float a[8], bv[8];
            *(float4*)&a[0]  = *(const float4*)&ksm[r][td];
            *(float4*)&a[4]  = *(const float4*)&ksm[r][td + 4];
            *(float4*)&bv[0] = *(const float4*)&vsm[r][te];
            *(float4*)&bv[4] = *(const float4*)&vsm[r][te + 4];
            #pragma unroll
            for (int i = 0; i < 8; ++i)
                #pragma unroll
                for (int j = 0; j < 8; ++j)
                    acc[i][j] = fmaf(a[i], bv[j], acc[i][j]);
        }
        __syncthreads();
    }
    float* kvp = kv + (size_t)bh * DD * DD;
    #pragma unroll
    for (int i = 0; i < 8; ++i)
        #pragma unroll
        for (int j = 0; j < 8; ++j)
            atomicAdd(&kvp[(td + i) * DD + te + j], acc[i][j] * (1.0f / 64.0f));
}

// ---------------------------------------------------------------------------
// K5: out[m, h*128+e] = z[m,h] * sum_d qr[m,h*128+d] * kv[b,h,d,e]
// block: 64 rows x 1 head (128 cols); writes attn into d_out (full coverage)
// ---------------------------------------------------------------------------
__global__ __launch_bounds__(256) void attn_out_kernel(
    const float* __restrict__ qr, const float* __restrict__ kv,
    const float* __restrict__ z, float* __restrict__ out)
{
    __shared__ float qsm[16][68];   // [k][m], padded
    __shared__ float kvs[16][128];  // [k][e]
    const int m0 = blockIdx.x * 64;
    const int h = blockIdx.y;
    const int b = m0 >> 12;
    const int tid = threadIdx.x;
    const int tm = (tid >> 4) * 4;
    const int tn = (tid & 15) * 8;
    const float* qp  = qr + (size_t)m0 * CC + h * DD;
    const float* kvp = kv + (size_t)(b * HH + h) * DD * DD;
    float acc[4][8] = {};
    for (int k0 = 0; k0 < DD; k0 += 16) {
        #pragma unroll
        for (int i = 0; i < 4; ++i) {
            int e = tid + i * 256;          // 64x16 q tile
            int r = e >> 4, c = e & 15;
            qsm[c][r] = qp[(size_t)r * CC + k0 + c];
        }
        #pragma unroll
        for (int i = 0; i < 8; ++i) {
            int e = tid + i * 256;          // 16x128 kv tile (2048 elems)
            int r = e >> 7, c = e & 127;
            kvs[r][c] = kvp[(k0 + r) * DD + c];
        }
        __syncthreads();
        #pragma unroll
        for (int kk = 0; kk < 16; ++kk) {
            float a[4], bv[8];
            *(float4*)&a[0]  = *(const float4*)&qsm[kk][tm];
            *(float4*)&bv[0] = *(const float4*)&kvs[kk][tn];
            *(float4*)&bv[4] = *(const float4*)&kvs[kk][tn + 4];
            #pragma unroll
            for (int i = 0; i < 4; ++i)
                #pragma unroll
                for (int j = 0; j < 8; ++j)
                    acc[i][j] = fmaf(a[i], bv[j], acc[i][j]);
        }
        __syncthreads();
    }
    #pragma unroll
    for (int i = 0; i < 4; ++i) {
        const int m = m0 + tm + i;
        const float zz = z[(size_t)m * HH + h];
        #pragma unroll
        for (int j = 0; j < 8; ++j)
            out[(size_t)m * CC + h * DD + tn + j] = acc[i][j] * zz;
    }
}

// ---------------------------------------------------------------------------
// K6: out += conv1d(x, lepe_w, SAME) + lepe_b
// GEMM with K=3072 (w-major: k = w*1024 + i), A rows shifted by w-1 with
// zero padding at batch-sequence boundaries. BK=16 never straddles w.
// ---------------------------------------------------------------------------
__global__ __launch_bounds__(256) void lepe_kernel(
    const float* __restrict__ x, const float* __restrict__ w,
    const float* __restrict__ bias, float* __restrict__ out)
{
    __shared__ float As[16][132];
    __shared__ float Bs[16][128];
    const int m0 = blockIdx.x * 128;
    const int n0 = blockIdx.y * 128;
    const int tid = threadIdx.x;
    const int tm = (tid >> 4) * 8;
    const int tn = (tid & 15) * 8;
    float acc[8][8] = {};
    for (int k0 = 0; k0 < 3 * CC; k0 += 16) {
        const int wtap = k0 >> 10;       // 0,1,2
        const int i0 = k0 & (CC - 1);
        const int shift = wtap - 1;      // -1,0,+1
        #pragma unroll
        for (int i = 0; i < 8; ++i) {
            int e = tid + i * 256;
            int r = e >> 4, c = e & 15;
            const int m = m0 + r;
            const int srcpos = (m & (NN - 1)) + shift;
            float v = 0.0f;
            if (srcpos >= 0 && srcpos < NN)
                v = x[(size_t)(m + shift) * CC + i0 + c];
            As[c][r] = v;
        }
        #pragma unroll
        for (int i = 0; i < 8; ++i) {
            int e = tid + i * 256;
            int r = e >> 7, c = e & 127;
            Bs[r][c] = w[(size_t)(k0 + r) * CC + (n0 + c)];
        }
        __syncthreads();
        #pragma unroll
        for (int kk = 0; kk < 16; ++kk) {
            float a[8], bv[8];
            *(float4*)&a[0]  = *(const float4*)&As[kk][tm];
            *(float4*)&a[4]  = *(const float4*)&As[kk][tm + 4];
            *(float4*)&bv[0] = *(const float4*)&Bs[kk][tn];
            *(float4*)&bv[4] = *(const float4*)&Bs[kk][tn + 4];
            #pragma unroll
            for (int i = 0; i < 8; ++i)
                #pragma unroll
                for (int j = 0; j < 8; ++j)
                    acc[i][j] = fmaf(a[i], bv[j], acc[i][j]);
        }
        __syncthreads();
    }
    #pragma unroll
    for (int i = 0; i < 8; ++i) {
        const int m = m0 + tm + i;
        #pragma unroll
        for (int j = 0; j < 8; ++j) {
            const int n = n0 + tn + j;
            out[(size_t)m * CC + n] += acc[i][j] + bias[n];
        }
    }
}

// ---------------------------------------------------------------------------
extern "C" void kernel_launch(void* const* d_in, const int* in_sizes, int n_in,
                              void* d_out, int out_size, void* d_ws, size_t ws_size,
                              hipStream_t stream)
{
    const float* x      = (const float*)d_in[0];
    const float* qk_w   = (const float*)d_in[1];
    const float* qk_b   = (const float*)d_in[2];
    const float* lepe_w = (const float*)d_in[3];
    const float* lepe_b = (const float*)d_in[4];
    float* out = (float*)d_out;

    // workspace layout (floats): 2*M*C + B*C + M*H + B*H*D*D  ~= 136.9 MB
    float* ws    = (float*)d_ws;
    float* qbuf  = ws;                              // M*C
    float* kbuf  = qbuf + (size_t)MM * CC;          // M*C
    float* kmean = kbuf + (size_t)MM * CC;          // B*C
    float* zbuf  = kmean + BB * CC;                 // M*H
    float* kvbuf = zbuf + (size_t)MM * HH;          // B*H*D*D

    hipMemsetAsync(kmean, 0, BB * CC * sizeof(float), stream);
    hipMemsetAsync(kvbuf, 0, (size_t)BB * HH * DD * DD * sizeof(float), stream);

    gemm_qk_kernel <<<dim3(MM / 128, 2048 / 128), 256, 0, stream>>>(x, qk_w, qk_b, qbuf, kbuf);
    kmean_kernel   <<<dim3(16, 64),               256, 0, stream>>>(kbuf, kmean);
    rope_z_kernel  <<<MM,                         256, 0, stream>>>(qbuf, kbuf, kmean, zbuf);
    kv_kernel      <<<dim3(32, 16),               256, 0, stream>>>(kbuf, x, kvbuf);
    attn_out_kernel<<<dim3(MM / 64, HH),          256, 0, stream>>>(qbuf, kvbuf, zbuf, out);
    lepe_kernel    <<<dim3(MM / 128, CC / 128),   256, 0, stream>>>(x, lepe_w, lepe_b, out);
}

// Round 3
// 924.667 us; speedup vs baseline: 3.1491x; 3.1491x over previous
//
#include <hip/hip_runtime.h>
#include <cmath>

#define BB 4
#define NN 4096
#define CC 1024
#define HH 8
#define DD 128
#define MM (BB*NN)   // 16384
#define NP (NN+2)    // padded rows per batch

typedef __attribute__((ext_vector_type(8))) short bf16x8;
typedef __attribute__((ext_vector_type(4))) float f32x4;

static __device__ __forceinline__ unsigned short f2bf(float f) {
    unsigned int u = __float_as_uint(f);
    unsigned int r = (u + 0x7FFF + ((u >> 16) & 1)) >> 16;
    return (unsigned short)r;
}

static __device__ __forceinline__ void load_lds16(const void* g, void* l) {
    __builtin_amdgcn_global_load_lds(
        (const __attribute__((address_space(1))) unsigned int*)g,
        (__attribute__((address_space(3))) unsigned int*)l, 16, 0, 0);
}

// ---------------------------------------------------------------------------
// P1: xpad[b][p][c] (bf16), p in [0,NP): row 0 and NP-1 are zeros,
//     row p = x[b][p-1].  One block per padded row.
// ---------------------------------------------------------------------------
__global__ __launch_bounds__(256) void padx_kernel(
    const float* __restrict__ x, unsigned short* __restrict__ xpad)
{
    const int r = blockIdx.x;                // 0 .. BB*NP-1
    const int b = r / NP, p = r % NP;
    const int c = threadIdx.x * 4;
    ushort4 v = {0, 0, 0, 0};
    if (p >= 1 && p <= NN) {
        const float4 f = *(const float4*)&x[(size_t)(b * NN + p - 1) * CC + c];
        v.x = f2bf(f.x); v.y = f2bf(f.y); v.z = f2bf(f.z); v.w = f2bf(f.w);
    }
    *(ushort4*)&xpad[(size_t)r * CC + c] = v;
}

// ---------------------------------------------------------------------------
// P2: dst[c][r] = bf16(src[r][c])  (transpose + convert), src R x Cc
// ---------------------------------------------------------------------------
__global__ __launch_bounds__(256) void transpose_bf16_kernel(
    const float* __restrict__ src, unsigned short* __restrict__ dst,
    int R, int Cc)
{
    __shared__ float t[32][33];
    const int r0 = blockIdx.y * 32, c0 = blockIdx.x * 32;
    const int tx = threadIdx.x & 31, ty = threadIdx.x >> 5;   // 8 rows/pass
    #pragma unroll
    for (int i = 0; i < 4; ++i) {
        int r = ty + i * 8;
        t[r][tx] = src[(size_t)(r0 + r) * Cc + c0 + tx];
    }
    __syncthreads();
    #pragma unroll
    for (int i = 0; i < 4; ++i) {
        int r = ty + i * 8;   // row within c-tile (output row)
        dst[(size_t)(c0 + r) * R + r0 + tx] = f2bf(t[tx][r]);
    }
}

// ---------------------------------------------------------------------------
// K1: qk = x @ qk_w + qk_b ; elu+1 ; split -> qbuf / kbuf   (bf16 MFMA)
// 128x128 tile, BK=32, 4 waves, each wave 64x64 = 4x4 MFMA 16x16x32 tiles.
// LDS layout: frag-contiguous 16B chunks; chunk(row,quad) = (row>>4)*64 +
// quad*16 + (row&15), so lane l of subtile MT reads chunk MT*64+l (b128,
// conflict-free). Staged via global_load_lds width=16.
// ---------------------------------------------------------------------------
__global__ __launch_bounds__(256) void gemm_qk_mfma(
    const unsigned short* __restrict__ xpad, const unsigned short* __restrict__ wT,
    const float* __restrict__ bias, float* __restrict__ qbuf,
    float* __restrict__ kbuf)
{
    __shared__ __align__(16) unsigned short As[4096];  // 128 x 32 bf16
    __shared__ __align__(16) unsigned short Bs[4096];  // 128(n) x 32(k) bf16
    const int m0 = blockIdx.x * 128;
    const int n0 = blockIdx.y * 128;
    const int tid = threadIdx.x;
    const int lane = tid & 63;
    const int wv = tid >> 6;
    const int rowoff = m0 + 1 + 2 * (m0 >> 12);        // xpad row of tile row 0

    f32x4 acc[4][4] = {};
    for (int k0 = 0; k0 < CC; k0 += 32) {
        #pragma unroll
        for (int p = 0; p < 2; ++p) {
            const int c = p * 256 + wv * 64 + lane;
            const int row = ((c >> 6) << 4) | (c & 15);
            const int quad = (c >> 4) & 3;
            load_lds16(&xpad[(size_t)(rowoff + row) * CC + k0 + quad * 8],
                       &As[(size_t)(p * 256 + wv * 64) * 8]);
            load_lds16(&wT[(size_t)(n0 + row) * CC + k0 + quad * 8],
                       &Bs[(size_t)(p * 256 + wv * 64) * 8]);
        }
        __syncthreads();
        bf16x8 a[4], b[4];
        #pragma unroll
        for (int mt = 0; mt < 4; ++mt)
            a[mt] = *(const bf16x8*)&As[(((wv & 1) * 4 + mt) * 64 + lane) * 8];
        #pragma unroll
        for (int nt = 0; nt < 4; ++nt)
            b[nt] = *(const bf16x8*)&Bs[(((wv >> 1) * 4 + nt) * 64 + lane) * 8];
        #pragma unroll
        for (int mt = 0; mt < 4; ++mt)
            #pragma unroll
            for (int nt = 0; nt < 4; ++nt)
                acc[mt][nt] = __builtin_amdgcn_mfma_f32_16x16x32_bf16(
                    a[mt], b[nt], acc[mt][nt], 0, 0, 0);
        __syncthreads();
    }
    const int wm = (wv & 1) * 64, wn = (wv >> 1) * 64;
    const int col = lane & 15, rbase = (lane >> 4) * 4;
    #pragma unroll
    for (int mt = 0; mt < 4; ++mt)
        #pragma unroll
        for (int nt = 0; nt < 4; ++nt)
            #pragma unroll
            for (int r = 0; r < 4; ++r) {
                const int m = m0 + wm + mt * 16 + rbase + r;
                const int n = n0 + wn + nt * 16 + col;
                float v = acc[mt][nt][r] + bias[n];
                v = (v > 0.0f) ? (v + 1.0f) : expf(v);   // elu(v)+1
                if (n < CC) qbuf[(size_t)m * CC + n] = v;
                else        kbuf[(size_t)m * CC + (n - CC)] = v;
            }
}

// ---------------------------------------------------------------------------
// K6: out += conv1d(x, lepe_w, SAME) + lepe_b   (implicit GEMM, bf16 MFMA)
// K = 3072 (w-major). BK=32 never straddles a tap; tap -> uniform row shift,
// boundary zeros come from xpad's pad rows.
// ---------------------------------------------------------------------------
__global__ __launch_bounds__(256) void lepe_mfma(
    const unsigned short* __restrict__ xpad, const unsigned short* __restrict__ wT,
    const float* __restrict__ bias, float* __restrict__ out)
{
    __shared__ __align__(16) unsigned short As[4096];
    __shared__ __align__(16) unsigned short Bs[4096];
    const int m0 = blockIdx.x * 128;
    const int n0 = blockIdx.y * 128;
    const int tid = threadIdx.x;
    const int lane = tid & 63;
    const int wv = tid >> 6;
    const int rowoff = m0 + 1 + 2 * (m0 >> 12);

    f32x4 acc[4][4] = {};
    for (int k0 = 0; k0 < 3 * CC; k0 += 32) {
        const int shift = (k0 >> 10) - 1;    // -1,0,+1
        const int i0 = k0 & (CC - 1);
        #pragma unroll
        for (int p = 0; p < 2; ++p) {
            const int c = p * 256 + wv * 64 + lane;
            const int row = ((c >> 6) << 4) | (c & 15);
            const int quad = (c >> 4) & 3;
            load_lds16(&xpad[(size_t)(rowoff + row + shift) * CC + i0 + quad * 8],
                       &As[(size_t)(p * 256 + wv * 64) * 8]);
            load_lds16(&wT[(size_t)(n0 + row) * (3 * CC) + k0 + quad * 8],
                       &Bs[(size_t)(p * 256 + wv * 64) * 8]);
        }
        __syncthreads();
        bf16x8 a[4], b[4];
        #pragma unroll
        for (int mt = 0; mt < 4; ++mt)
            a[mt] = *(const bf16x8*)&As[(((wv & 1) * 4 + mt) * 64 + lane) * 8];
        #pragma unroll
        for (int nt = 0; nt < 4; ++nt)
            b[nt] = *(const bf16x8*)&Bs[(((wv >> 1) * 4 + nt) * 64 + lane) * 8];
        #pragma unroll
        for (int mt = 0; mt < 4; ++mt)
            #pragma unroll
            for (int nt = 0; nt < 4; ++nt)
                acc[mt][nt] = __builtin_amdgcn_mfma_f32_16x16x32_bf16(
                    a[mt], b[nt], acc[mt][nt], 0, 0, 0);
        __syncthreads();
    }
    const int wm = (wv & 1) * 64, wn = (wv >> 1) * 64;
    const int col = lane & 15, rbase = (lane >> 4) * 4;
    #pragma unroll
    for (int mt = 0; mt < 4; ++mt)
        #pragma unroll
        for (int nt = 0; nt < 4; ++nt)
            #pragma unroll
            for (int r = 0; r < 4; ++r) {
                const int m = m0 + wm + mt * 16 + rbase + r;
                const int n = n0 + wn + nt * 16 + col;
                out[(size_t)m * CC + n] += acc[mt][nt][r] + bias[n];
            }
}

// ---------------------------------------------------------------------------
// K2: kmean[b,c] = mean over n of kbuf[b,n,c]
// ---------------------------------------------------------------------------
__global__ __launch_bounds__(256) void kmean_kernel(
    const float* __restrict__ kbuf, float* __restrict__ kmean)
{
    const int b = blockIdx.x >> 2;
    const int c = (blockIdx.x & 3) * 256 + threadIdx.x;
    const int n0 = blockIdx.y * 64;
    const float* p = kbuf + (size_t)(b * NN + n0) * CC + c;
    float s = 0.0f;
    for (int r = 0; r < 64; ++r) s += p[(size_t)r * CC];
    atomicAdd(&kmean[b * CC + c], s * (1.0f / (float)NN));
}

// ---------------------------------------------------------------------------
// K3: z[m,h] = 1/(dot(q_head, kmean_head)+1e-6) (pre-rope q); RoPE q,k in place
// ---------------------------------------------------------------------------
__global__ __launch_bounds__(256) void rope_z_kernel(
    float* __restrict__ qbuf, float* __restrict__ kbuf,
    const float* __restrict__ kmean, float* __restrict__ zbuf)
{
    __shared__ float qs[CC];
    __shared__ float ks2[CC];
    __shared__ float zsum[HH];
    const int m = blockIdx.x;
    const int b = m >> 12;
    const int pos = m & (NN - 1);
    const int tid = threadIdx.x;
    float* qrow = qbuf + (size_t)m * CC;
    float* krow = kbuf + (size_t)m * CC;
    const float* km = kmean + b * CC;
    for (int i = tid; i < CC; i += 256) { qs[i] = qrow[i]; ks2[i] = krow[i]; }
    if (tid < HH) zsum[tid] = 0.0f;
    __syncthreads();
    {
        const int c0 = tid * 4;
        float p = 0.0f;
        #pragma unroll
        for (int i = 0; i < 4; ++i) p = fmaf(qs[c0 + i], km[c0 + i], p);
        atomicAdd(&zsum[tid >> 5], p);
    }
    #pragma unroll
    for (int jj = 0; jj < 2; ++jj) {
        const int j = tid + jj * 256;   // 0..511
        const float theta = 1.0f / powf(10000.0f, (float)j * (1.0f / 512.0f));
        float sv, cv;
        sincosf((float)pos * theta, &sv, &cv);
        const float q0 = qs[2 * j], q1 = qs[2 * j + 1];
        const float k0 = ks2[2 * j], k1 = ks2[2 * j + 1];
        qrow[j]       = cv * q0 - sv * q1;
        qrow[j + 512] = cv * q1 + sv * q0;
        krow[j]       = cv * k0 - sv * k1;
        krow[j + 512] = cv * k1 + sv * k0;
    }
    __syncthreads();
    if (tid < HH) zbuf[(size_t)m * HH + tid] = 1.0f / (zsum[tid] + 1e-6f);
}

// ---------------------------------------------------------------------------
// K4: kv[b,h,d,e] = (1/64) * sum_n kr[b,n,h,d] * x[b,n,h,e]  (split-n atomics)
// ---------------------------------------------------------------------------
__global__ __launch_bounds__(256) void kv_kernel(
    const float* __restrict__ kr, const float* __restrict__ x,
    float* __restrict__ kv)
{
    __shared__ float ksm[8][128];
    __shared__ float vsm[8][128];
    const int bh = blockIdx.x;
    const int b = bh >> 3, h = bh & 7;
    const int n0 = blockIdx.y * 256;
    const int tid = threadIdx.x;
    const int td = (tid >> 4) * 8;
    const int te = (tid & 15) * 8;
    const float* krp = kr + (size_t)(b * NN + n0) * CC + h * DD;
    const float* xp  = x  + (size_t)(b * NN + n0) * CC + h * DD;
    float acc[8][8] = {};
    for (int r0 = 0; r0 < 256; r0 += 8) {
        #pragma unroll
        for (int i = 0; i < 4; ++i) {
            int e = tid + i * 256;
            int r = e >> 7, c = e & 127;
            ksm[r][c] = krp[(size_t)(r0 + r) * CC + c];
            vsm[r][c] = xp[(size_t)(r0 + r) * CC + c];
        }
        __syncthreads();
        #pragma unroll
        for (int r = 0; r < 8; ++r) {
            float a[8], bv[8];
            *(float4*)&a[0]  = *(const float4*)&ksm[r][td];
            *(float4*)&a[4]  = *(const float4*)&ksm[r][td + 4];
            *(float4*)&bv[0] = *(const float4*)&vsm[r][te];
            *(float4*)&bv[4] = *(const float4*)&vsm[r][te + 4];
            #pragma unroll
            for (int i = 0; i < 8; ++i)
                #pragma unroll
                for (int j = 0; j < 8; ++j)
                    acc[i][j] = fmaf(a[i], bv[j], acc[i][j]);
        }
        __syncthreads();
    }
    float* kvp = kv + (size_t)bh * DD * DD;
    #pragma unroll
    for (int i = 0; i < 8; ++i)
        #pragma unroll
        for (int j = 0; j < 8; ++j)
            atomicAdd(&kvp[(td + i) * DD + te + j], acc[i][j] * (1.0f / 64.0f));
}

// ---------------------------------------------------------------------------
// K5: out[m, h*128+e] = z[m,h] * sum_d qr[m,h*128+d] * kv[b,h,d,e]
// ---------------------------------------------------------------------------
__global__ __launch_bounds__(256) void attn_out_kernel(
    const float* __restrict__ qr, const float* __restrict__ kv,
    const float* __restrict__ z, float* __restrict__ out)
{
    __shared__ float qsm[16][68];
    __shared__ float kvs[16][128];
    const int m0 = blockIdx.x * 64;
    const int h = blockIdx.y;
    const int b = m0 >> 12;
    const int tid = threadIdx.x;
    const int tm = (tid >> 4) * 4;
    const int tn = (tid & 15) * 8;
    const float* qp  = qr + (size_t)m0 * CC + h * DD;
    const float* kvp = kv + (size_t)(b * HH + h) * DD * DD;
    float acc[4][8] = {};
    for (int k0 = 0; k0 < DD; k0 += 16) {
        #pragma unroll
        for (int i = 0; i < 4; ++i) {
            int e = tid + i * 256;
            int r = e >> 4, c = e & 15;
            qsm[c][r] = qp[(size_t)r * CC + k0 + c];
        }
        #pragma unroll
        for (int i = 0; i < 8; ++i) {
            int e = tid + i * 256;
            int r = e >> 7, c = e & 127;
            kvs[r][c] = kvp[(k0 + r) * DD + c];
        }
        __syncthreads();
        #pragma unroll
        for (int kk = 0; kk < 16; ++kk) {
            float a[4], bv[8];
            *(float4*)&a[0]  = *(const float4*)&qsm[kk][tm];
            *(float4*)&bv[0] = *(const float4*)&kvs[kk][tn];
            *(float4*)&bv[4] = *(const float4*)&kvs[kk][tn + 4];
            #pragma unroll
            for (int i = 0; i < 4; ++i)
                #pragma unroll
                for (int j = 0; j < 8; ++j)
                    acc[i][j] = fmaf(a[i], bv[j], acc[i][j]);
        }
        __syncthreads();
    }
    #pragma unroll
    for (int i = 0; i < 4; ++i) {
        const int m = m0 + tm + i;
        const float zz = z[(size_t)m * HH + h];
        #pragma unroll
        for (int j = 0; j < 8; ++j)
            out[(size_t)m * CC + h * DD + tn + j] = acc[i][j] * zz;
    }
}

// ---------------------------------------------------------------------------
extern "C" void kernel_launch(void* const* d_in, const int* in_sizes, int n_in,
                              void* d_out, int out_size, void* d_ws, size_t ws_size,
                              hipStream_t stream)
{
    const float* x      = (const float*)d_in[0];
    const float* qk_w   = (const float*)d_in[1];
    const float* qk_b   = (const float*)d_in[2];
    const float* lepe_w = (const float*)d_in[3];
    const float* lepe_b = (const float*)d_in[4];
    float* out = (float*)d_out;

    // fp32 region
    float* ws    = (float*)d_ws;
    float* qbuf  = ws;                              // M*C
    float* kbuf  = qbuf + (size_t)MM * CC;          // M*C
    float* kmean = kbuf + (size_t)MM * CC;          // B*C
    float* zbuf  = kmean + BB * CC;                 // M*H
    float* kvbuf = zbuf + (size_t)MM * HH;          // B*H*D*D
    // bf16 region
    unsigned short* xpad = (unsigned short*)(kvbuf + (size_t)BB * HH * DD * DD);
    unsigned short* wqT  = xpad + (size_t)BB * NP * CC;       // [2048][1024]
    unsigned short* wlT  = wqT + (size_t)2 * CC * CC;         // [1024][3072]

    hipMemsetAsync(kmean, 0, BB * CC * sizeof(float), stream);
    hipMemsetAsync(kvbuf, 0, (size_t)BB * HH * DD * DD * sizeof(float), stream);

    padx_kernel          <<<BB * NP,             256, 0, stream>>>(x, xpad);
    transpose_bf16_kernel<<<dim3(2 * CC / 32, CC / 32), 256, 0, stream>>>(qk_w, wqT, CC, 2 * CC);
    transpose_bf16_kernel<<<dim3(CC / 32, 3 * CC / 32), 256, 0, stream>>>(lepe_w, wlT, 3 * CC, CC);

    gemm_qk_mfma   <<<dim3(MM / 128, 2048 / 128), 256, 0, stream>>>(xpad, wqT, qk_b, qbuf, kbuf);
    kmean_kernel   <<<dim3(16, 64),               256, 0, stream>>>(kbuf, kmean);
    rope_z_kernel  <<<MM,                         256, 0, stream>>>(qbuf, kbuf, kmean, zbuf);
    kv_kernel      <<<dim3(32, 16),               256, 0, stream>>>(kbuf, x, kvbuf);
    attn_out_kernel<<<dim3(MM / 64, HH),          256, 0, stream>>>(qbuf, kvbuf, zbuf, out);
    lepe_mfma      <<<dim3(MM / 128, CC / 128),   256, 0, stream>>>(xpad, wlT, lepe_b, out);
}

// Round 4
// 763.174 us; speedup vs baseline: 3.8154x; 1.2116x over previous
//
#include <hip/hip_runtime.h>
#include <cmath>

#define BB 4
#define NN 4096
#define CC 1024
#define HH 8
#define DD 128
#define MM (BB*NN)   // 16384
#define NP (NN+2)    // padded rows per batch

typedef __attribute__((ext_vector_type(8))) short bf16x8;
typedef __attribute__((ext_vector_type(4))) float f32x4;

static __device__ __forceinline__ unsigned short f2bf(float f) {
    unsigned int u = __float_as_uint(f);
    unsigned int r = (u + 0x7FFF + ((u >> 16) & 1)) >> 16;
    return (unsigned short)r;
}
static __device__ __forceinline__ float bf2f(short s) {
    return __uint_as_float(((unsigned int)(unsigned short)s) << 16);
}
static __device__ __forceinline__ float4 bf4(ushort4 u) {
    float4 f;
    f.x = __uint_as_float((unsigned int)u.x << 16);
    f.y = __uint_as_float((unsigned int)u.y << 16);
    f.z = __uint_as_float((unsigned int)u.z << 16);
    f.w = __uint_as_float((unsigned int)u.w << 16);
    return f;
}

static __device__ __forceinline__ void load_lds16(const void* g, void* l) {
    __builtin_amdgcn_global_load_lds(
        (const __attribute__((address_space(1))) unsigned int*)g,
        (__attribute__((address_space(3))) unsigned int*)l, 16, 0, 0);
}

// ---------------------------------------------------------------------------
// P1: xpad[b][p][c] (bf16), p in [0,NP): rows 0 and NP-1 zero, p = x[b][p-1]
// ---------------------------------------------------------------------------
__global__ __launch_bounds__(256) void padx_kernel(
    const float* __restrict__ x, unsigned short* __restrict__ xpad)
{
    const int r = blockIdx.x;
    const int b = r / NP, p = r % NP;
    const int c = threadIdx.x * 4;
    ushort4 v = {0, 0, 0, 0};
    if (p >= 1 && p <= NN) {
        const float4 f = *(const float4*)&x[(size_t)(b * NN + p - 1) * CC + c];
        v.x = f2bf(f.x); v.y = f2bf(f.y); v.z = f2bf(f.z); v.w = f2bf(f.w);
    }
    *(ushort4*)&xpad[(size_t)r * CC + c] = v;
}

// ---------------------------------------------------------------------------
// P2: dst[c][r] = bf16(src[r][c])
// ---------------------------------------------------------------------------
__global__ __launch_bounds__(256) void transpose_bf16_kernel(
    const float* __restrict__ src, unsigned short* __restrict__ dst,
    int R, int Cc)
{
    __shared__ float t[32][33];
    const int r0 = blockIdx.y * 32, c0 = blockIdx.x * 32;
    const int tx = threadIdx.x & 31, ty = threadIdx.x >> 5;
    #pragma unroll
    for (int i = 0; i < 4; ++i) {
        int r = ty + i * 8;
        t[r][tx] = src[(size_t)(r0 + r) * Cc + c0 + tx];
    }
    __syncthreads();
    #pragma unroll
    for (int i = 0; i < 4; ++i) {
        int r = ty + i * 8;
        dst[(size_t)(c0 + r) * R + r0 + tx] = f2bf(t[tx][r]);
    }
}

// ---------------------------------------------------------------------------
// K1: qk = x @ qk_w + qk_b ; elu+1 ; q,k stored bf16; k column sums -> ksum
// ---------------------------------------------------------------------------
__global__ __launch_bounds__(256) void gemm_qk_mfma(
    const unsigned short* __restrict__ xpad, const unsigned short* __restrict__ wT,
    const float* __restrict__ bias, unsigned short* __restrict__ qbuf,
    unsigned short* __restrict__ kbuf, float* __restrict__ ksum)
{
    __shared__ __align__(16) unsigned short As[4096];  // 128 x 32 bf16
    __shared__ __align__(16) unsigned short Bs[4096];
    const int m0 = blockIdx.x * 128;
    const int n0 = blockIdx.y * 128;
    const int tid = threadIdx.x;
    const int lane = tid & 63;
    const int wv = tid >> 6;
    const int rowoff = m0 + 1 + 2 * (m0 >> 12);

    f32x4 acc[4][4] = {};
    for (int k0 = 0; k0 < CC; k0 += 32) {
        #pragma unroll
        for (int p = 0; p < 2; ++p) {
            const int c = p * 256 + wv * 64 + lane;
            const int row = ((c >> 6) << 4) | (c & 15);
            const int quad = (c >> 4) & 3;
            load_lds16(&xpad[(size_t)(rowoff + row) * CC + k0 + quad * 8],
                       &As[(size_t)(p * 256 + wv * 64) * 8]);
            load_lds16(&wT[(size_t)(n0 + row) * CC + k0 + quad * 8],
                       &Bs[(size_t)(p * 256 + wv * 64) * 8]);
        }
        __syncthreads();
        bf16x8 a[4], b[4];
        #pragma unroll
        for (int mt = 0; mt < 4; ++mt)
            a[mt] = *(const bf16x8*)&As[(((wv & 1) * 4 + mt) * 64 + lane) * 8];
        #pragma unroll
        for (int nt = 0; nt < 4; ++nt)
            b[nt] = *(const bf16x8*)&Bs[(((wv >> 1) * 4 + nt) * 64 + lane) * 8];
        #pragma unroll
        for (int mt = 0; mt < 4; ++mt)
            #pragma unroll
            for (int nt = 0; nt < 4; ++nt)
                acc[mt][nt] = __builtin_amdgcn_mfma_f32_16x16x32_bf16(
                    a[mt], b[nt], acc[mt][nt], 0, 0, 0);
        __syncthreads();
    }
    const int wm = (wv & 1) * 64, wn = (wv >> 1) * 64;
    const int col = lane & 15, rbase = (lane >> 4) * 4;
    const bool khalf = (n0 >= CC);
    const int b = m0 >> 12;
    #pragma unroll
    for (int nt = 0; nt < 4; ++nt) {
        const int n = n0 + wn + nt * 16 + col;
        const float bn = bias[n];
        float csum = 0.0f;
        #pragma unroll
        for (int mt = 0; mt < 4; ++mt)
            #pragma unroll
            for (int r = 0; r < 4; ++r) {
                const int m = m0 + wm + mt * 16 + rbase + r;
                float v = acc[mt][nt][r] + bn;
                v = (v > 0.0f) ? (v + 1.0f) : expf(v);   // elu(v)+1
                csum += v;
                if (!khalf) qbuf[(size_t)m * CC + n] = f2bf(v);
                else        kbuf[(size_t)m * CC + (n - CC)] = f2bf(v);
            }
        if (khalf) atomicAdd(&ksum[b * CC + (n - CC)], csum);
    }
}

// ---------------------------------------------------------------------------
// K3: thread = (row, head). z[m,h] = 1/(dot(q_head, ksum_head)/N + 1e-6);
// RoPE q in place (barrier-ordered); kr -> krP[b][h][n][d] bf16.
// ---------------------------------------------------------------------------
__global__ __launch_bounds__(256) void rope_z_kernel(
    unsigned short* __restrict__ qbuf, const unsigned short* __restrict__ kbuf,
    const float* __restrict__ ksum, unsigned short* __restrict__ krP,
    float* __restrict__ zbuf)
{
    const int tid = threadIdx.x;
    const int row = tid >> 3;            // 0..31
    const int h = tid & 7;
    const int m = blockIdx.x * 32 + row;
    const int b = m >> 12;
    const int pos = m & (NN - 1);
    unsigned short* qrow = qbuf + (size_t)m * CC + h * DD;
    const unsigned short* krow = kbuf + (size_t)m * CC + h * DD;

    bf16x8 qv[16], kv8[16];
    #pragma unroll
    for (int i = 0; i < 16; ++i) {
        qv[i]  = *(const bf16x8*)&qrow[i * 8];
        kv8[i] = *(const bf16x8*)&krow[i * 8];
    }
    // z from pre-rope q
    const float* km = ksum + b * CC + h * DD;
    float dot = 0.0f;
    #pragma unroll
    for (int i = 0; i < 16; ++i)
        #pragma unroll
        for (int jq = 0; jq < 8; ++jq)
            dot = fmaf(bf2f(qv[i][jq]), km[i * 8 + jq], dot);
    dot *= (1.0f / (float)NN);
    __syncthreads();   // all q reads complete before in-place writes
    zbuf[(size_t)m * HH + h] = 1.0f / (dot + 1e-6f);

    #pragma unroll
    for (int c8 = 0; c8 < 8; ++c8) {
        bf16x8 qpr, qpi, kpr, kpi;
        #pragma unroll
        for (int u = 0; u < 8; ++u) {
            const int jj = c8 * 8 + u;
            const int j = h * 64 + jj;           // global pair index 0..511
            const float theta = __builtin_exp2f((float)j * (-13.287712379549449f / 512.0f));
            float sv, cv;
            sincosf((float)pos * theta, &sv, &cv);
            const int li = c8 * 2 + (u >> 2);
            const int le = (2 * u) & 7;
            const float q0 = bf2f(qv[li][le]),  q1 = bf2f(qv[li][le + 1]);
            const float k0 = bf2f(kv8[li][le]), k1 = bf2f(kv8[li][le + 1]);
            qpr[u] = (short)f2bf(cv * q0 - sv * q1);
            qpi[u] = (short)f2bf(cv * q1 + sv * q0);
            kpr[u] = (short)f2bf(cv * k0 - sv * k1);
            kpi[u] = (short)f2bf(cv * k1 + sv * k0);
        }
        *(bf16x8*)&qbuf[(size_t)m * CC + h * 64 + c8 * 8] = qpr;
        *(bf16x8*)&qbuf[(size_t)m * CC + 512 + h * 64 + c8 * 8] = qpi;
        unsigned short* kp1 = &krP[((size_t)(b * 8 + (h >> 1)) * NN + pos) * DD + (h & 1) * 64 + c8 * 8];
        unsigned short* kp2 = &krP[((size_t)(b * 8 + 4 + (h >> 1)) * NN + pos) * DD + (h & 1) * 64 + c8 * 8];
        *(bf16x8*)kp1 = kpr;
        *(bf16x8*)kp2 = kpi;
    }
}

// ---------------------------------------------------------------------------
// K4: kvpart[slice][bh][d][e] = sum over slice's 256 n of kr[n,d]*v[n,e]
// bf16 inputs (krP, xpad); fp32 LDS staging; NO atomics.
// ---------------------------------------------------------------------------
__global__ __launch_bounds__(256) void kv_kernel(
    const unsigned short* __restrict__ krP, const unsigned short* __restrict__ xpad,
    float* __restrict__ kvpart)
{
    __shared__ float ksm[8][132];
    __shared__ float vsm[8][132];
    const int bh = blockIdx.x;                 // 0..31
    const int slice = blockIdx.y;              // 0..15
    const int b = bh >> 3, h = bh & 7;
    const int n0 = slice * 256;
    const int tid = threadIdx.x;
    const int td = (tid >> 4) * 8;
    const int te = (tid & 15) * 8;
    const unsigned short* kp = krP + ((size_t)bh * NN + n0) * DD;
    const unsigned short* vp = xpad + ((size_t)(b * NP) + 1 + n0) * CC + h * DD;
    const int sr = tid >> 5;                   // staging row 0..7
    const int sc = (tid & 31) * 4;             // staging col
    float acc[8][8] = {};
    for (int r0 = 0; r0 < 256; r0 += 8) {
        const ushort4 kq = *(const ushort4*)&kp[(size_t)(r0 + sr) * DD + sc];
        const ushort4 vq = *(const ushort4*)&vp[(size_t)(r0 + sr) * CC + sc];
        *(float4*)&ksm[sr][sc] = bf4(kq);
        *(float4*)&vsm[sr][sc] = bf4(vq);
        __syncthreads();
        #pragma unroll
        for (int r = 0; r < 8; ++r) {
            float a[8], bv[8];
            *(float4*)&a[0]  = *(const float4*)&ksm[r][td];
            *(float4*)&a[4]  = *(const float4*)&ksm[r][td + 4];
            *(float4*)&bv[0] = *(const float4*)&vsm[r][te];
            *(float4*)&bv[4] = *(const float4*)&vsm[r][te + 4];
            #pragma unroll
            for (int i = 0; i < 8; ++i)
                #pragma unroll
                for (int j = 0; j < 8; ++j)
                    acc[i][j] = fmaf(a[i], bv[j], acc[i][j]);
        }
        __syncthreads();
    }
    float* op = kvpart + ((size_t)slice * 32 + bh) * (DD * DD);
    #pragma unroll
    for (int i = 0; i < 8; ++i)
        #pragma unroll
        for (int j = 0; j < 8; j += 4)
            *(float4*)&op[(td + i) * DD + te + j] = *(float4*)&acc[i][j];
}

// ---------------------------------------------------------------------------
// K4b: kvred = (1/64) * sum over 16 slices
// ---------------------------------------------------------------------------
__global__ __launch_bounds__(256) void kv_reduce_kernel(
    const float* __restrict__ kvpart, float* __restrict__ kvred)
{
    const size_t i = ((size_t)blockIdx.x * 256 + threadIdx.x) * 4;
    float4 s = {0.0f, 0.0f, 0.0f, 0.0f};
    #pragma unroll
    for (int sl = 0; sl < 16; ++sl) {
        const float4 v = *(const float4*)&kvpart[(size_t)sl * (32 * DD * DD) + i];
        s.x += v.x; s.y += v.y; s.z += v.z; s.w += v.w;
    }
    s.x *= (1.0f / 64.0f); s.y *= (1.0f / 64.0f);
    s.z *= (1.0f / 64.0f); s.w *= (1.0f / 64.0f);
    *(float4*)&kvred[i] = s;
}

// ---------------------------------------------------------------------------
// K5: out[m, h*128+e] = z[m,h] * sum_d qr[m,h*128+d] * kv[b,h,d,e]
// ---------------------------------------------------------------------------
__global__ __launch_bounds__(256) void attn_out_kernel(
    const unsigned short* __restrict__ qr, const float* __restrict__ kv,
    const float* __restrict__ z, float* __restrict__ out)
{
    __shared__ float qsm[16][68];
    __shared__ float kvs[16][128];
    const int m0 = blockIdx.x * 64;
    const int h = blockIdx.y;
    const int b = m0 >> 12;
    const int tid = threadIdx.x;
    const int tm = (tid >> 4) * 4;
    const int tn = (tid & 15) * 8;
    const unsigned short* qp = qr + (size_t)m0 * CC + h * DD;
    const float* kvp = kv + (size_t)(b * HH + h) * DD * DD;
    float acc[4][8] = {};
    for (int k0 = 0; k0 < DD; k0 += 16) {
        #pragma unroll
        for (int i = 0; i < 4; ++i) {
            int e = tid + i * 256;
            int r = e >> 4, c = e & 15;
            qsm[c][r] = bf2f(qp[(size_t)r * CC + k0 + c]);
        }
        #pragma unroll
        for (int i = 0; i < 8; ++i) {
            int e = tid + i * 256;
            int r = e >> 7, c = e & 127;
            kvs[r][c] = kvp[(k0 + r) * DD + c];
        }
        __syncthreads();
        #pragma unroll
        for (int kk = 0; kk < 16; ++kk) {
            float a[4], bv[8];
            *(float4*)&a[0]  = *(const float4*)&qsm[kk][tm];
            *(float4*)&bv[0] = *(const float4*)&kvs[kk][tn];
            *(float4*)&bv[4] = *(const float4*)&kvs[kk][tn + 4];
            #pragma unroll
            for (int i = 0; i < 4; ++i)
                #pragma unroll
                for (int j = 0; j < 8; ++j)
                    acc[i][j] = fmaf(a[i], bv[j], acc[i][j]);
        }
        __syncthreads();
    }
    #pragma unroll
    for (int i = 0; i < 4; ++i) {
        const int m = m0 + tm + i;
        const float zz = z[(size_t)m * HH + h];
        #pragma unroll
        for (int j = 0; j < 8; ++j)
            out[(size_t)m * CC + h * DD + tn + j] = acc[i][j] * zz;
    }
}

// ---------------------------------------------------------------------------
// K6: out += conv1d(x, lepe_w, SAME) + lepe_b   (implicit GEMM, bf16 MFMA)
// ---------------------------------------------------------------------------
__global__ __launch_bounds__(256) void lepe_mfma(
    const unsigned short* __restrict__ xpad, const unsigned short* __restrict__ wT,
    const float* __restrict__ bias, float* __restrict__ out)
{
    __shared__ __align__(16) unsigned short As[4096];
    __shared__ __align__(16) unsigned short Bs[4096];
    const int m0 = blockIdx.x * 128;
    const int n0 = blockIdx.y * 128;
    const int tid = threadIdx.x;
    const int lane = tid & 63;
    const int wv = tid >> 6;
    const int rowoff = m0 + 1 + 2 * (m0 >> 12);

    f32x4 acc[4][4] = {};
    for (int k0 = 0; k0 < 3 * CC; k0 += 32) {
        const int shift = (k0 >> 10) - 1;
        const int i0 = k0 & (CC - 1);
        #pragma unroll
        for (int p = 0; p < 2; ++p) {
            const int c = p * 256 + wv * 64 + lane;
            const int row = ((c >> 6) << 4) | (c & 15);
            const int quad = (c >> 4) & 3;
            load_lds16(&xpad[(size_t)(rowoff + row + shift) * CC + i0 + quad * 8],
                       &As[(size_t)(p * 256 + wv * 64) * 8]);
            load_lds16(&wT[(size_t)(n0 + row) * (3 * CC) + k0 + quad * 8],
                       &Bs[(size_t)(p * 256 + wv * 64) * 8]);
        }
        __syncthreads();
        bf16x8 a[4], b[4];
        #pragma unroll
        for (int mt = 0; mt < 4; ++mt)
            a[mt] = *(const bf16x8*)&As[(((wv & 1) * 4 + mt) * 64 + lane) * 8];
        #pragma unroll
        for (int nt = 0; nt < 4; ++nt)
            b[nt] = *(const bf16x8*)&Bs[(((wv >> 1) * 4 + nt) * 64 + lane) * 8];
        #pragma unroll
        for (int mt = 0; mt < 4; ++mt)
            #pragma unroll
            for (int nt = 0; nt < 4; ++nt)
                acc[mt][nt] = __builtin_amdgcn_mfma_f32_16x16x32_bf16(
                    a[mt], b[nt], acc[mt][nt], 0, 0, 0);
        __syncthreads();
    }
    const int wm = (wv & 1) * 64, wn = (wv >> 1) * 64;
    const int col = lane & 15, rbase = (lane >> 4) * 4;
    #pragma unroll
    for (int mt = 0; mt < 4; ++mt)
        #pragma unroll
        for (int nt = 0; nt < 4; ++nt)
            #pragma unroll
            for (int r = 0; r < 4; ++r) {
                const int m = m0 + wm + mt * 16 + rbase + r;
                const int n = n0 + wn + nt * 16 + col;
                out[(size_t)m * CC + n] += acc[mt][nt][r] + bias[n];
            }
}

// ---------------------------------------------------------------------------
extern "C" void kernel_launch(void* const* d_in, const int* in_sizes, int n_in,
                              void* d_out, int out_size, void* d_ws, size_t ws_size,
                              hipStream_t stream)
{
    const float* x      = (const float*)d_in[0];
    const float* qk_w   = (const float*)d_in[1];
    const float* qk_b   = (const float*)d_in[2];
    const float* lepe_w = (const float*)d_in[3];
    const float* lepe_b = (const float*)d_in[4];
    float* out = (float*)d_out;

    // fp32 region
    float* ws     = (float*)d_ws;
    float* zbuf   = ws;                                   // MM*HH
    float* ksum   = zbuf + (size_t)MM * HH;               // BB*CC
    float* kvred  = ksum + (size_t)BB * CC;               // 32*128*128
    float* kvpart = kvred + (size_t)32 * DD * DD;         // 16*32*128*128
    // bf16 region
    unsigned short* xpad = (unsigned short*)(kvpart + (size_t)16 * 32 * DD * DD);
    unsigned short* wqT  = xpad + (size_t)BB * NP * CC;   // [2048][1024]
    unsigned short* wlT  = wqT + (size_t)2 * CC * CC;     // [1024][3072]
    unsigned short* qbuf = wlT + (size_t)CC * 3 * CC;     // M*C (q, then qr in place)
    unsigned short* kbuf = qbuf + (size_t)MM * CC;        // M*C
    unsigned short* krP  = kbuf + (size_t)MM * CC;        // [32][4096][128]

    hipMemsetAsync(ksum, 0, BB * CC * sizeof(float), stream);

    padx_kernel          <<<BB * NP,                      256, 0, stream>>>(x, xpad);
    transpose_bf16_kernel<<<dim3(2 * CC / 32, CC / 32),   256, 0, stream>>>(qk_w, wqT, CC, 2 * CC);
    transpose_bf16_kernel<<<dim3(CC / 32, 3 * CC / 32),   256, 0, stream>>>(lepe_w, wlT, 3 * CC, CC);

    gemm_qk_mfma    <<<dim3(MM / 128, 2048 / 128), 256, 0, stream>>>(xpad, wqT, qk_b, qbuf, kbuf, ksum);
    rope_z_kernel   <<<MM / 32,                    256, 0, stream>>>(qbuf, kbuf, ksum, krP, zbuf);
    kv_kernel       <<<dim3(32, 16),               256, 0, stream>>>(krP, xpad, kvpart);
    kv_reduce_kernel<<<(32 * DD * DD / 4) / 256,   256, 0, stream>>>(kvpart, kvred);
    attn_out_kernel <<<dim3(MM / 64, HH),          256, 0, stream>>>(qbuf, kvred, zbuf, out);
    lepe_mfma       <<<dim3(MM / 128, CC / 128),   256, 0, stream>>>(xpad, wlT, lepe_b, out);
}